// Round 15
// baseline (39.589 us; speedup 1.0000x reference)
//
#include <hip/hip_runtime.h>
#include <hip/hip_fp16.h>

#define NI 65536
#define NO 65536
#define NW 32
#define NB 32

typedef float  fx4 __attribute__((ext_vector_type(4)));
typedef float  fx2 __attribute__((ext_vector_type(2)));
typedef int    ix4 __attribute__((ext_vector_type(4)));
typedef uint   ux4 __attribute__((ext_vector_type(4)));
typedef ushort sx4 __attribute__((ext_vector_type(4)));

// xTh[i][b]  : fp16 x column i (64B record)          — 4 MB
// fwmh[i][w] : fp16(fw*fm)                           — 4 MB
// fmb[i] bit w = (fm[i][w] != 0)                     — 256 KB
// P[o][slot] = i<<16 | fp16(s), compacted, 0-padded  — 8 MB

// ---- kernel 1: build xTh + fwmh + fmb ----
__global__ __launch_bounds__(256) void dsm_prep(
    const float* __restrict__ x, const float* __restrict__ fw,
    const float* __restrict__ fm, ushort* __restrict__ xTh,
    ushort* __restrict__ fwmh, uint* __restrict__ fmb)
{
    __shared__ float tile[32][33];
    __shared__ uint  lfmb[32];
    const int tid = threadIdx.x;
    const int tx = tid & 31, ty = tid >> 5;
    const int i0 = blockIdx.x * 32;

    if (tid < 32) lfmb[tid] = 0;
#pragma unroll
    for (int r = 0; r < 4; ++r) {
        const int b = ty + 8 * r;
        tile[b][tx] = __builtin_nontemporal_load(&x[(size_t)b * NI + i0 + tx]);
    }
    __syncthreads();
#pragma unroll
    for (int r = 0; r < 4; ++r) {
        const int ii = ty + 8 * r;
        xTh[(size_t)(i0 + ii) * NB + tx] =
            __half_as_ushort(__float2half(tile[tx][ii]));
    }
    const size_t base = (size_t)blockIdx.x * 1024 + (size_t)tid * 4;
    const fx4 a = __builtin_nontemporal_load((const fx4*)(fw + base));
    const fx4 m = __builtin_nontemporal_load((const fx4*)(fm + base));
    sx4 h;
    h.x = __half_as_ushort(__float2half(a.x * m.x));
    h.y = __half_as_ushort(__float2half(a.y * m.y));
    h.z = __half_as_ushort(__float2half(a.z * m.z));
    h.w = __half_as_ushort(__float2half(a.w * m.w));
    *(sx4*)(fwmh + base) = h;

    const uint bits = (m.x != 0.f ? 1u : 0u) | (m.y != 0.f ? 2u : 0u)
                    | (m.z != 0.f ? 4u : 0u) | (m.w != 0.f ? 8u : 0u);
    atomicOr(&lfmb[tid >> 3], bits << ((tid & 7) * 4));
    __syncthreads();
    if (tid < 32) fmb[blockIdx.x * 32 + tid] = lfmb[tid];
}

// ---- kernel 2 (pack): wave = 16 rows x 4 lanes; block = 64 o's.
//      Filter via fmb + ballot compaction, then survivor-only s-gather
//      (ONLY random table: fwmh, 4MB = L2-resident), nt-store P. ----
__global__ __launch_bounds__(256) void dsm_pack(
    const int*    __restrict__ om,
    const float*  __restrict__ rm,
    const ushort* __restrict__ fwmh,
    const uint*   __restrict__ fmb,
    uint* __restrict__ P)
{
    __shared__ uint sp[4][576];        // per-wave 16 rows, stride 36
    const int tid  = threadIdx.x;
    const int wave = tid >> 6;
    const int lane = tid & 63;
    const int row  = lane >> 2;
    const int c    = lane & 3;
    const int o_block = blockIdx.x * 64;
    const int o_wave  = o_block + wave * 16;

#pragma unroll
    for (int k = lane; k < 576; k += 64) sp[wave][k] = 0;

    int cnt = 0;
    {
        const size_t ebase = (size_t)o_wave * NW + (size_t)lane * 8;
        const ix4 iv0 = __builtin_nontemporal_load((const ix4*)(om + ebase));
        const ix4 iv1 = __builtin_nontemporal_load((const ix4*)(om + ebase + 4));
        const fx4 rv0 = __builtin_nontemporal_load((const fx4*)(rm + ebase));
        const fx4 rv1 = __builtin_nontemporal_load((const fx4*)(rm + ebase + 4));
        const int w0 = c * 8;
        uint  ii[8]; float rr[8]; uint fb[8];
#pragma unroll
        for (int j = 0; j < 8; ++j) {
            ii[j] = (uint)((j < 4) ? iv0[j] : iv1[j - 4]) & 0xffffu;
            rr[j] = (j < 4) ? rv0[j] : rv1[j - 4];
        }
#pragma unroll
        for (int j = 0; j < 8; ++j) fb[j] = fmb[ii[j]];

        const unsigned long long rowmask  = 0xFull << (row * 4);
        const unsigned long long beforeme = (1ull << lane) - 1ull;
#pragma unroll
        for (int j = 0; j < 8; ++j) {
            const uint keep = (rr[j] != 0.0f) & ((fb[j] >> (w0 + j)) & 1u);
            const unsigned long long bl = __ballot(keep != 0u);
            const int pos = cnt + __popcll(bl & rowmask & beforeme);
            if (keep) sp[wave][row * 36 + pos] = (ii[j] << 16) | (uint)(w0 + j);
            cnt += __popcll(bl & rowmask);
        }
    }
    // s-fill on compacted (dense) slots: random gathers into L2-resident fwmh
    for (int t = c; t < cnt; t += 4) {
        const uint key = sp[wave][row * 36 + t];
        const uint i = key >> 16, w = key & 31u;
        sp[wave][row * 36 + t] = (i << 16) | (uint)fwmh[i * NW + w];
    }
    __syncthreads();
    // coalesced nt-store of the wave's 16 rows (512 uints)
#pragma unroll
    for (int it = 0; it < 2; ++it) {
        const int idx = it * 256 + lane * 4;
        const int r = idx >> 5, s = idx & 31;
        ux4 v;
#pragma unroll
        for (int j = 0; j < 4; ++j) v[j] = sp[wave][r * 36 + s + j];
        __builtin_nontemporal_store(v,
            (ux4*)(P + (size_t)o_block * NW + wave * 512 + idx));
    }
}

// ---- kernel 3 (main): wave = 16 rows x 4 lanes (16B/lane); block = 64 o's.
//      Streams P (nt), gathers ONLY xTh (4MB = L2-resident). ----
__global__ __launch_bounds__(256) void dsm_main(
    const uint*   __restrict__ P,
    const ushort* __restrict__ xTh,    // [NI][32] fp16, 64B records
    float* __restrict__ out)           // [NB][NO]
{
    __shared__ uint sp[4][576];
    const int tid  = threadIdx.x;
    const int wave = tid >> 6;
    const int lane = tid & 63;
    const int row  = lane >> 2;
    const int c    = lane & 3;         // 16B chunk: b = 8c..8c+7
    const int o_block = blockIdx.x * 64;

    // stage P rows -> LDS (coalesced nt loads, b128 LDS writes)
#pragma unroll
    for (int it = 0; it < 2; ++it) {
        const int idx = it * 256 + lane * 4;
        const ux4 v = __builtin_nontemporal_load(
            (const ux4*)(P + (size_t)o_block * NW + wave * 512 + idx));
        const int r = idx >> 5, s = idx & 31;
        *(ux4*)(&sp[wave][r * 36 + s]) = v;
    }
    __syncthreads();

    fx2 a0 = {0.f, 0.f}, a1 = {0.f, 0.f}, a2 = {0.f, 0.f}, a3 = {0.f, 0.f};
    {
        const uint* spw = &sp[wave][row * 36];
#pragma unroll
        for (int wc = 0; wc < NW; wc += 4) {
            const ux4 k4 = *(const ux4*)(spw + wc);    // ds_read_b128 broadcast
            if (__all((k4[0] | k4[1] | k4[2] | k4[3]) == 0u)) break;
#pragma unroll
            for (int j = 0; j < 4; ++j) {
                const uint p = k4[j];
                const uint i = p >> 16;
                const float sv = __half2float(__ushort_as_half((ushort)(p & 0xffffu)));
                const fx2 s2 = {sv, sv};
                const ux4 xv = *(const ux4*)(xTh + i * NB + (uint)c * 8u); // 16B
#pragma unroll
                for (int k = 0; k < 4; ++k) {
                    fx2 xk;
                    xk.x = __half2float(__ushort_as_half((ushort)(xv[k] & 0xffffu)));
                    xk.y = __half2float(__ushort_as_half((ushort)(xv[k] >> 16)));
                    if (k == 0) a0 = s2 * xk + a0;
                    else if (k == 1) a1 = s2 * xk + a1;
                    else if (k == 2) a2 = s2 * xk + a2;
                    else a3 = s2 * xk + a3;
                }
            }
        }
    }
    __syncthreads();                   // reuse sp as out tile

    float* tile = (float*)sp;          // 2304 uints >= 32*65
    const int ocol = wave * 16 + row;
    tile[(c * 8 + 0) * 65 + ocol] = a0.x;
    tile[(c * 8 + 1) * 65 + ocol] = a0.y;
    tile[(c * 8 + 2) * 65 + ocol] = a1.x;
    tile[(c * 8 + 3) * 65 + ocol] = a1.y;
    tile[(c * 8 + 4) * 65 + ocol] = a2.x;
    tile[(c * 8 + 5) * 65 + ocol] = a2.y;
    tile[(c * 8 + 6) * 65 + ocol] = a3.x;
    tile[(c * 8 + 7) * 65 + ocol] = a3.y;
    __syncthreads();
    {
        const int col = tid & 63;
#pragma unroll
        for (int r = 0; r < 8; ++r) {
            const int b = (tid >> 6) + 4 * r;
            __builtin_nontemporal_store(tile[b * 65 + col],
                                        &out[(size_t)b * NO + o_block + col]);
        }
    }
}

// ---- fallback (no workspace): direct fp32, half-wave per o ----
__global__ __launch_bounds__(256) void dsm_fallback(
    const float* __restrict__ x, const float* __restrict__ fw,
    const float* __restrict__ fm, const int* __restrict__ om,
    const float* __restrict__ rm, float* __restrict__ out)
{
    const int tid = threadIdx.x;
    const int l = tid & 31, hw = tid >> 5;
    const int o = blockIdx.x * 8 + hw;
    const int i_l = om[(size_t)o * NW + l];
    const float s_l = fw[(size_t)i_l * NW + l] * fm[(size_t)i_l * NW + l]
                    * rm[(size_t)o * NW + l];
    float acc = 0.f;
#pragma unroll
    for (int w = 0; w < NW; ++w) {
        const int   i = __shfl(i_l, w, 32);
        const float s = __shfl(s_l, w, 32);
        acc = fmaf(s, x[(size_t)l * NI + i], acc);
    }
    out[(size_t)l * NO + o] = acc;
}

extern "C" void kernel_launch(void* const* d_in, const int* in_sizes, int n_in,
                              void* d_out, int out_size, void* d_ws, size_t ws_size,
                              hipStream_t stream) {
    const float* x  = (const float*)d_in[0];
    const float* fw = (const float*)d_in[1];
    const float* fm = (const float*)d_in[2];
    const int*   om = (const int*)d_in[3];
    const float* rm = (const float*)d_in[4];
    float* out = (float*)d_out;

    const size_t needXT = (size_t)NI * NB * sizeof(ushort);  // 4 MB
    const size_t needFW = (size_t)NI * NW * sizeof(ushort);  // 4 MB
    const size_t needFB = (size_t)NI * sizeof(uint);         // 256 KB
    const size_t needP  = (size_t)NO * NW * sizeof(uint);    // 8 MB

    if (ws_size >= needXT + needFW + needFB + needP) {
        ushort* xTh  = (ushort*)d_ws;
        ushort* fwmh = (ushort*)((char*)d_ws + needXT);
        uint*   fmb  = (uint*)((char*)d_ws + needXT + needFW);
        uint*   P    = (uint*)((char*)d_ws + needXT + needFW + needFB);
        dsm_prep<<<dim3(NI / 32), 256, 0, stream>>>(x, fw, fm, xTh, fwmh, fmb);
        dsm_pack<<<dim3(NO / 64), 256, 0, stream>>>(om, rm, fwmh, fmb, P);
        dsm_main<<<dim3(NO / 64), 256, 0, stream>>>(P, xTh, out);
    } else {
        dsm_fallback<<<dim3(NO / 8), 256, 0, stream>>>(x, fw, fm, om, rm, out);
    }
}

// Round 16
// 35.205 us; speedup vs baseline: 1.1245x; 1.1245x over previous
//
#include <hip/hip_runtime.h>
#include <hip/hip_fp16.h>

#define NI 65536
#define NO 65536
#define NW 32
#define NB 32

typedef float  fx4 __attribute__((ext_vector_type(4)));
typedef int    ix4 __attribute__((ext_vector_type(4)));
typedef uint   ux4 __attribute__((ext_vector_type(4)));
typedef ushort sx4 __attribute__((ext_vector_type(4)));

// T[i] = 128B record (64 ushorts): [0:32) = x column i (fp16, b=0..31),
//                                  [32:64) = fp16(fw*fm) row i (w=0..31).
// fmb[i] bit w = (fm[i][w] != 0).

union u2h { uint u; __half2 h2; };

// ---- kernel 1: build T + fmb ----
__global__ __launch_bounds__(256) void dsm_prep(
    const float* __restrict__ x, const float* __restrict__ fw,
    const float* __restrict__ fm, ushort* __restrict__ T16,
    uint* __restrict__ fmb)
{
    __shared__ float tile[32][33];
    __shared__ uint  lfmb[32];
    const int tid = threadIdx.x;
    const int tx = tid & 31, ty = tid >> 5;
    const int i0 = blockIdx.x * 32;

    if (tid < 32) lfmb[tid] = 0;
#pragma unroll
    for (int r = 0; r < 4; ++r) {
        const int b = ty + 8 * r;
        tile[b][tx] = __builtin_nontemporal_load(&x[(size_t)b * NI + i0 + tx]);
    }
    __syncthreads();
#pragma unroll
    for (int r = 0; r < 4; ++r) {
        const int ii = ty + 8 * r;
        T16[(size_t)(i0 + ii) * 64 + tx] =
            __half_as_ushort(__float2half(tile[tx][ii]));
    }
    // fw*fm -> fp16 into record upper half; fm bitmap
    const size_t base = (size_t)blockIdx.x * 1024 + (size_t)tid * 4;
    const int row = i0 + (tid >> 3);
    const int w0  = (tid & 7) * 4;
    const fx4 a = __builtin_nontemporal_load((const fx4*)(fw + base));
    const fx4 m = __builtin_nontemporal_load((const fx4*)(fm + base));
    sx4 h;
    h.x = __half_as_ushort(__float2half(a.x * m.x));
    h.y = __half_as_ushort(__float2half(a.y * m.y));
    h.z = __half_as_ushort(__float2half(a.z * m.z));
    h.w = __half_as_ushort(__float2half(a.w * m.w));
    *(sx4*)(T16 + (size_t)row * 64 + 32 + w0) = h;

    const uint bits = (m.x != 0.f ? 1u : 0u) | (m.y != 0.f ? 2u : 0u)
                    | (m.z != 0.f ? 4u : 0u) | (m.w != 0.f ? 8u : 0u);
    atomicOr(&lfmb[tid >> 3], bits << w0);
    __syncthreads();
    if (tid < 32) fmb[blockIdx.x * 32 + tid] = lfmb[tid];
}

// ---- kernel 2 (fused): r11 structure. wave = 16 o-rows x 4 lanes (16B/lane).
//      Phase A: filter (fmb only) + ballot compaction; key = i<<16|valid<<5|w.
//      Phase B: s and x from the SAME 128B T-record line; PACKED fp16
//      accumulation (v_pk_fma_f16) — no per-survivor cvt. Block = 64 o's. ----
__global__ __launch_bounds__(256) void dsm_fused(
    const int*    __restrict__ om,
    const float*  __restrict__ rm,
    const ushort* __restrict__ T16,    // [NI] 128B records
    const uint*   __restrict__ fmb,    // [NI] bitmap
    float* __restrict__ out)           // [NB][NO]
{
    __shared__ uint sp[4][576];        // per-wave 16 rows, stride 36
    const int tid  = threadIdx.x;
    const int wave = tid >> 6;
    const int lane = tid & 63;
    const int row  = lane >> 2;        // o sub-index within wave (0..15)
    const int c    = lane & 3;         // 16B chunk: b = 8c..8c+7
    const int o_block = blockIdx.x * 64;
    const int o_wave  = o_block + wave * 16;

#pragma unroll
    for (int k = lane; k < 576; k += 64) sp[wave][k] = 0;

    // ---- phase A: filter + compaction (no value gathers) ----
    int cnt = 0;
    {
        const size_t ebase = (size_t)o_wave * NW + (size_t)lane * 8;
        const ix4 iv0 = __builtin_nontemporal_load((const ix4*)(om + ebase));
        const ix4 iv1 = __builtin_nontemporal_load((const ix4*)(om + ebase + 4));
        const fx4 rv0 = __builtin_nontemporal_load((const fx4*)(rm + ebase));
        const fx4 rv1 = __builtin_nontemporal_load((const fx4*)(rm + ebase + 4));
        const int w0 = c * 8;
        uint  ii[8]; float rr[8]; uint fb[8];
#pragma unroll
        for (int j = 0; j < 8; ++j) {
            ii[j] = (uint)((j < 4) ? iv0[j] : iv1[j - 4]) & 0xffffu;
            rr[j] = (j < 4) ? rv0[j] : rv1[j - 4];
        }
#pragma unroll
        for (int j = 0; j < 8; ++j) fb[j] = fmb[ii[j]];

        const unsigned long long rowmask  = 0xFull << (row * 4);
        const unsigned long long beforeme = (1ull << lane) - 1ull;
#pragma unroll
        for (int j = 0; j < 8; ++j) {
            const uint keep = (rr[j] != 0.0f) & ((fb[j] >> (w0 + j)) & 1u);
            const unsigned long long bl = __ballot(keep != 0u);
            const int pos = cnt + __popcll(bl & rowmask & beforeme);
            if (keep)
                sp[wave][row * 36 + pos] = (ii[j] << 16) | 0x20u | (uint)(w0 + j);
            cnt += __popcll(bl & rowmask);
        }
    }
    __syncthreads();

    // ---- phase B: one 128B line per survivor; packed-fp16 accumulate ----
    __half2 h0 = __float2half2_rn(0.f), h1 = h0, h2 = h0, h3 = h0;
    {
        const uint* spw = &sp[wave][row * 36];
        const int nw = (cnt + 3) & ~3;       // uniform within 4-lane group
        for (int t = 0; t < nw; t += 4) {
            const ux4 k4 = *(const ux4*)(spw + t);   // ds_read_b128 broadcast
#pragma unroll
            for (int j = 0; j < 4; ++j) {
                const uint p = k4[j];
                const uint i = p >> 16;
                const uint w = p & 31u;
                ushort hs = T16[i * 64u + 32u + w];
                hs = (p & 0x20u) ? hs : (ushort)0;   // pad slots contribute 0
                const __half2 s2 = __half2half2(__ushort_as_half(hs));
                const ux4 xv = *(const ux4*)(T16 + i * 64u + (uint)c * 8u);
                u2h x0, x1, x2, x3;
                x0.u = xv[0]; x1.u = xv[1]; x2.u = xv[2]; x3.u = xv[3];
                h0 = __hfma2(s2, x0.h2, h0);
                h1 = __hfma2(s2, x1.h2, h1);
                h2 = __hfma2(s2, x2.h2, h2);
                h3 = __hfma2(s2, x3.h2, h3);
            }
        }
    }
    __syncthreads();                   // all waves done with their sp segments

    // ---- epilogue: tile (32 b x 64 o-cols, stride 65) then coalesced store ----
    float* tile = (float*)sp;          // 2304 uints >= 32*65
    const int ocol = wave * 16 + row;
    tile[(c * 8 + 0) * 65 + ocol] = __low2float(h0);
    tile[(c * 8 + 1) * 65 + ocol] = __high2float(h0);
    tile[(c * 8 + 2) * 65 + ocol] = __low2float(h1);
    tile[(c * 8 + 3) * 65 + ocol] = __high2float(h1);
    tile[(c * 8 + 4) * 65 + ocol] = __low2float(h2);
    tile[(c * 8 + 5) * 65 + ocol] = __high2float(h2);
    tile[(c * 8 + 6) * 65 + ocol] = __low2float(h3);
    tile[(c * 8 + 7) * 65 + ocol] = __high2float(h3);
    __syncthreads();
    {
        const int col = tid & 63;
#pragma unroll
        for (int r = 0; r < 8; ++r) {
            const int b = (tid >> 6) + 4 * r;
            __builtin_nontemporal_store(tile[b * 65 + col],
                                        &out[(size_t)b * NO + o_block + col]);
        }
    }
}

// ---- fallback (no workspace): direct fp32, half-wave per o ----
__global__ __launch_bounds__(256) void dsm_fallback(
    const float* __restrict__ x, const float* __restrict__ fw,
    const float* __restrict__ fm, const int* __restrict__ om,
    const float* __restrict__ rm, float* __restrict__ out)
{
    const int tid = threadIdx.x;
    const int l = tid & 31, hw = tid >> 5;
    const int o = blockIdx.x * 8 + hw;
    const int i_l = om[(size_t)o * NW + l];
    const float s_l = fw[(size_t)i_l * NW + l] * fm[(size_t)i_l * NW + l]
                    * rm[(size_t)o * NW + l];
    float acc = 0.f;
#pragma unroll
    for (int w = 0; w < NW; ++w) {
        const int   i = __shfl(i_l, w, 32);
        const float s = __shfl(s_l, w, 32);
        acc = fmaf(s, x[(size_t)l * NI + i], acc);
    }
    out[(size_t)l * NO + o] = acc;
}

extern "C" void kernel_launch(void* const* d_in, const int* in_sizes, int n_in,
                              void* d_out, int out_size, void* d_ws, size_t ws_size,
                              hipStream_t stream) {
    const float* x  = (const float*)d_in[0];
    const float* fw = (const float*)d_in[1];
    const float* fm = (const float*)d_in[2];
    const int*   om = (const int*)d_in[3];
    const float* rm = (const float*)d_in[4];
    float* out = (float*)d_out;

    const size_t needT  = (size_t)NI * 64 * sizeof(ushort);  // 8 MB
    const size_t needFB = (size_t)NI * sizeof(uint);         // 256 KB

    if (ws_size >= needT + needFB) {
        ushort* T16 = (ushort*)d_ws;
        uint*   fmb = (uint*)((char*)d_ws + needT);
        dsm_prep<<<dim3(NI / 32), 256, 0, stream>>>(x, fw, fm, T16, fmb);
        dsm_fused<<<dim3(NO / 64), 256, 0, stream>>>(om, rm, T16, fmb, out);
    } else {
        dsm_fallback<<<dim3(NO / 8), 256, 0, stream>>>(x, fw, fm, om, rm, out);
    }
}